// Round 6
// baseline (179.361 us; speedup 1.0000x reference)
//
#include <hip/hip_runtime.h>
#include <math.h>

#define T_ 128
#define NPROJ 2176  // cols: [0,512)=Q [512,1024)=K [1024,1536)=V [1536,1600)=beta [1600,1664)=tg*rho [1664,2176)=gate
#define CH 32       // scan chunk

typedef __attribute__((ext_vector_type(8))) short short8;
typedef __attribute__((ext_vector_type(4))) float float4v;
typedef __attribute__((ext_vector_type(16))) float f32x16;

__device__ __forceinline__ ushort f2bf(float x) {
    unsigned u = __float_as_uint(x);
    u += 0x7FFF + ((u >> 16) & 1);   // RNE
    return (ushort)(u >> 16);
}
__device__ __forceinline__ float bfu(ushort u) { return __uint_as_float(((unsigned)u) << 16); }

// ---------------- Kernel 1: prep = params + x->bf16 + W/Wo transpose + Acomb zero -----
__global__ __launch_bounds__(256) void prep_kernel(
    const float* __restrict__ x,
    const float* __restrict__ Wq, const float* __restrict__ Wk,
    const float* __restrict__ Wv, const float* __restrict__ Wb,
    const float* __restrict__ Wtg, const float* __restrict__ Wg,
    const float* __restrict__ Wo,
    const float* __restrict__ mode_logits, const float* __restrict__ log_decay,
    const float* __restrict__ ols,
    float* __restrict__ cosw, float* __restrict__ sinw, float* __restrict__ omg,
    float* __restrict__ rho, float* __restrict__ modew,
    ushort* __restrict__ xb, ushort* __restrict__ wtb, ushort* __restrict__ wotb,
    float* __restrict__ Acomb)
{
    __shared__ ushort tile[64][68];
    const int blk = blockIdx.x, tid = threadIdx.x;
    if (blk < 16) {
        int idx = blk * 256 + tid;
        if (idx >= 64 * 64) return;
        int t = idx >> 6;   // hr
        int k = idx & 63;
        int h = t >> 3;
        if (k == 0) {
            float ld = log_decay[t];
            rho[t] = 1.0f / (1.0f + expf(ld));  // exp(-softplus) == sigmoid(-x)
            float m = -1e30f;
            for (int i = 0; i < 8; i++) m = fmaxf(m, mode_logits[h * 8 + i]);
            float sum = 0.0f;
            for (int i = 0; i < 8; i++) sum += expf(mode_logits[h * 8 + i] - m);
            modew[t] = expf(mode_logits[t] - m) / sum;
        }
        float osc = expf(ols[t]);
        int p = k >> 1;
        float invf = expf(-((float)(2 * p) / 64.0f) * logf(10000.0f));
        float w = osc * invf;
        cosw[idx] = cosf(w);
        sinw[idx] = sinf(w);
        omg[idx] = w;
        return;
    }
    if (blk < 80) {   // x convert
        int base = (blk - 16) * 4096 + tid * 16;
        float4 f0 = *(const float4*)&x[base];
        float4 f1 = *(const float4*)&x[base + 4];
        float4 f2 = *(const float4*)&x[base + 8];
        float4 f3 = *(const float4*)&x[base + 12];
        short8 o0, o1;
        o0[0]=f2bf(f0.x); o0[1]=f2bf(f0.y); o0[2]=f2bf(f0.z); o0[3]=f2bf(f0.w);
        o0[4]=f2bf(f1.x); o0[5]=f2bf(f1.y); o0[6]=f2bf(f1.z); o0[7]=f2bf(f1.w);
        o1[0]=f2bf(f2.x); o1[1]=f2bf(f2.y); o1[2]=f2bf(f2.z); o1[3]=f2bf(f2.w);
        o1[4]=f2bf(f3.x); o1[5]=f2bf(f3.y); o1[6]=f2bf(f3.z); o1[7]=f2bf(f3.w);
        *(short8*)&xb[base] = o0;
        *(short8*)&xb[base + 8] = o1;
        return;
    }
    if (blk >= 752) {  // zero Acomb
        int base = (blk - 752) * 4096 + tid * 16;
        float4 z = make_float4(0.f, 0.f, 0.f, 0.f);
        *(float4*)&Acomb[base] = z;
        *(float4*)&Acomb[base + 4] = z;
        *(float4*)&Acomb[base + 8] = z;
        *(float4*)&Acomb[base + 12] = z;
        return;
    }
    // transpose-convert
    const float* src; int ld, c0, n0, k0, ldd; ushort* dst;
    if (blk < 624) {
        int b3 = blk - 80; int nt = b3 >> 4, kt = b3 & 15;
        n0 = nt * 64; k0 = kt * 64;
        if (n0 < 512)       { src = Wq;  c0 = n0;        ld = 512; }
        else if (n0 < 1024) { src = Wk;  c0 = n0 - 512;  ld = 512; }
        else if (n0 < 1536) { src = Wv;  c0 = n0 - 1024; ld = 512; }
        else if (n0 < 1600) { src = Wb;  c0 = n0 - 1536; ld = 64;  }
        else if (n0 < 1664) { src = Wtg; c0 = n0 - 1600; ld = 64;  }
        else                { src = Wg;  c0 = n0 - 1664; ld = 512; }
        dst = wtb; ldd = 1024;
    } else {
        int b4 = blk - 624; int nt = b4 >> 3, kt = b4 & 7;
        n0 = nt * 64; k0 = kt * 64;
        src = Wo; c0 = n0; ld = 1024; dst = wotb; ldd = 512;
    }
    #pragma unroll
    for (int rep = 0; rep < 4; rep++) {
        int k = rep * 16 + (tid >> 4);
        int nc = (tid & 15) * 4;
        float4 f = *(const float4*)&src[(size_t)(k0 + k) * ld + c0 + nc];
        tile[nc + 0][k] = f2bf(f.x);
        tile[nc + 1][k] = f2bf(f.y);
        tile[nc + 2][k] = f2bf(f.z);
        tile[nc + 3][k] = f2bf(f.w);
    }
    __syncthreads();
    #pragma unroll
    for (int rep = 0; rep < 4; rep++) {
        int n = rep * 16 + (tid >> 4);
        int kc = (tid & 15) * 4;
        uint2 uu = *(const uint2*)&tile[n][kc];
        *(uint2*)&dst[(size_t)(n0 + n) * ldd + k0 + kc] = uu;
    }
}

// ---------------- Kernel 2: proj MFMA GEMM (depth-2 prefetch, NAMED regs) -------------
__global__ __launch_bounds__(256, 2) void proj_mfma(const ushort* __restrict__ Ab,
        const ushort* __restrict__ BTb, const float* __restrict__ rho,
        float* __restrict__ proj)
{
    __shared__ ushort sA[2][64][40];
    __shared__ ushort sB[2][64][40];
    const int n0 = blockIdx.x * 64, m0 = blockIdx.y * 64;
    const int tid = threadIdx.x;
    const int lane = tid & 63, w = tid >> 6;
    const int wm = w & 1, wn = w >> 1;
    const int l16 = lane & 15, quad = lane >> 4;
    const int srow = tid >> 2, skq = (tid & 3) * 8;
    const ushort* Ag = Ab + (size_t)(m0 + srow) * 1024 + skq;
    const ushort* Bg = BTb + (size_t)(n0 + srow) * 1024 + skq;
    short8 raA = *(const short8*)Ag;
    short8 rbA = *(const short8*)Bg;
    short8 raB = *(const short8*)(Ag + 32);
    short8 rbB = *(const short8*)(Bg + 32);
    float4v acc00 = {0,0,0,0}, acc01 = {0,0,0,0}, acc10 = {0,0,0,0}, acc11 = {0,0,0,0};
    for (int kt = 0; kt < 32; kt += 2) {
        *(short8*)&sA[0][srow][skq] = raA;
        *(short8*)&sB[0][srow][skq] = rbA;
        __syncthreads();
        if (kt + 2 < 32) {
            raA = *(const short8*)(Ag + (kt + 2) * 32);
            rbA = *(const short8*)(Bg + (kt + 2) * 32);
        }
        {
            short8 a0 = *(const short8*)&sA[0][wm * 32 + l16][quad * 8];
            short8 a1 = *(const short8*)&sA[0][wm * 32 + 16 + l16][quad * 8];
            short8 b0 = *(const short8*)&sB[0][wn * 32 + l16][quad * 8];
            short8 b1 = *(const short8*)&sB[0][wn * 32 + 16 + l16][quad * 8];
            acc00 = __builtin_amdgcn_mfma_f32_16x16x32_bf16(a0, b0, acc00, 0, 0, 0);
            acc01 = __builtin_amdgcn_mfma_f32_16x16x32_bf16(a0, b1, acc01, 0, 0, 0);
            acc10 = __builtin_amdgcn_mfma_f32_16x16x32_bf16(a1, b0, acc10, 0, 0, 0);
            acc11 = __builtin_amdgcn_mfma_f32_16x16x32_bf16(a1, b1, acc11, 0, 0, 0);
        }
        *(short8*)&sA[1][srow][skq] = raB;
        *(short8*)&sB[1][srow][skq] = rbB;
        __syncthreads();
        if (kt + 3 < 32) {
            raB = *(const short8*)(Ag + (kt + 3) * 32);
            rbB = *(const short8*)(Bg + (kt + 3) * 32);
        }
        {
            short8 a0 = *(const short8*)&sA[1][wm * 32 + l16][quad * 8];
            short8 a1 = *(const short8*)&sA[1][wm * 32 + 16 + l16][quad * 8];
            short8 b0 = *(const short8*)&sB[1][wn * 32 + l16][quad * 8];
            short8 b1 = *(const short8*)&sB[1][wn * 32 + 16 + l16][quad * 8];
            acc00 = __builtin_amdgcn_mfma_f32_16x16x32_bf16(a0, b0, acc00, 0, 0, 0);
            acc01 = __builtin_amdgcn_mfma_f32_16x16x32_bf16(a0, b1, acc01, 0, 0, 0);
            acc10 = __builtin_amdgcn_mfma_f32_16x16x32_bf16(a1, b0, acc10, 0, 0, 0);
            acc11 = __builtin_amdgcn_mfma_f32_16x16x32_bf16(a1, b1, acc11, 0, 0, 0);
        }
    }
    const bool sig = (n0 >= 1536);
    float m0c = 1.0f, m1c = 1.0f;
    if (n0 == 1600) {
        m0c = rho[wn * 32 + l16];
        m1c = rho[wn * 32 + l16 + 16];
    }
    const int colb = n0 + wn * 32 + l16;
    const int rowb = m0 + wm * 32 + quad * 4;
    #pragma unroll
    for (int r2 = 0; r2 < 4; r2++) {
        float v00 = acc00[r2], v01 = acc01[r2], v10 = acc10[r2], v11 = acc11[r2];
        if (sig) {
            v00 = m0c / (1.0f + expf(-v00));
            v01 = m1c / (1.0f + expf(-v01));
            v10 = m0c / (1.0f + expf(-v10));
            v11 = m1c / (1.0f + expf(-v11));
        }
        proj[(size_t)(rowb + r2) * NPROJ + colb] = v00;
        proj[(size_t)(rowb + r2) * NPROJ + colb + 16] = v01;
        proj[(size_t)(rowb + 16 + r2) * NPROJ + colb] = v10;
        proj[(size_t)(rowb + 16 + r2) * NPROJ + colb + 16] = v11;
    }
}

// ---------------- Kernel 3: chunked delta-rule scan via MFMA --------------------------
// grid 256 = b(2) x hr(64) x vhalf(2); block 256 (4 waves). 4 chunks of 32 steps.
// State Y = Omega * Z (once-rotated), bf16 hi/lo frags; imag part stored NEGATED.
// mfma_f32_32x32x16_bf16 frag convention (consistent builder map everywhere):
//   A: m = lane&31, k = s*16 + (lane>>5)*8 + j ; B: n = lane&31, k same
//   C: n = lane&31, m = (reg&3) + 8*(reg>>2) + 4*(lane>>5)
__global__ __launch_bounds__(256, 2) void scan_kernel(const float* __restrict__ proj,
        const float* __restrict__ cosw, const float* __restrict__ sinw,
        const float* __restrict__ omg, const float* __restrict__ modew,
        float* __restrict__ Acomb)
{
    __shared__ float omgl[64], cw64[64], sw64[64], c31x[64], s31x[64];
    __shared__ float bvec[32], ldl[32], lcp[32];
    __shared__ float vpl[32][33];
    __shared__ float Mm[32][36];      // beta-folded, strict-lower masked
    __shared__ float T1k[32][33];
    __shared__ short8 fragKc[4][64], fragKs[4][64], fragQc[4][64], fragQs[4][64];
    __shared__ short8 fragZ[4][4][64];   // [Yrh,Yrl,-Yih,-Yil][s][lane]
    __shared__ short8 fragW[2][2][2][64];// [r/i][ktile][s][lane]
    __shared__ short8 fragA[2][64];
    __shared__ short8 fragN[2][64];

    const int bi = blockIdx.x;
    const int vh = bi & 1;
    const int hr = (bi >> 1) & 63;
    const int b  = bi >> 7;
    const int h = hr >> 3, r = hr & 7;
    const int tid = threadIdx.x;
    const int wid = tid >> 6, lane = tid & 63;
    const int l31 = lane & 31, hi = lane >> 5;

    const float* pb = proj + (size_t)b * T_ * NPROJ;
    const int qcol = h * 64;
    const int kcol = 512 + h * 64;
    const int vcol = 1024 + h * 64 + vh * 32;
    const int gcol = 1664 + h * 64 + vh * 32;
    const int bcol = 1536 + h * 8 + r;
    const int dcol = 1600 + h * 8 + r;
    const float mw = modew[hr];

    // ---- P0: per-block tables + zero state ----
    if (tid < 64) {
        int k = tid;
        float w = omg[hr * 64 + k];
        omgl[k] = w;
        cw64[k] = cosw[hr * 64 + k];
        sw64[k] = sinw[hr * 64 + k];
        c31x[k] = cosf(31.0f * w);
        s31x[k] = sinf(31.0f * w);
    }
    for (int i = tid; i < 4 * 4 * 64 * 4; i += 256) ((float*)fragZ)[i] = 0.0f;
    __syncthreads();

    for (int c = 0; c < 4; c++) {
        const int t0 = c * 32;
        f32x16 accT;   // wave1's T1q accumulator, carried P2 -> P4
        #pragma unroll
        for (int i = 0; i < 16; i++) accT[i] = 0.0f;

        // ---- P1a: stage beta, log2(decay), v ----
        if (tid < 32) {
            int t = tid;
            bvec[t] = pb[(size_t)(t0 + t) * NPROJ + bcol];
            ldl[t]  = log2f(pb[(size_t)(t0 + t) * NPROJ + dcol]);
        }
        {
            int t = tid >> 3, vq = (tid & 7) * 4;
            float4 f = *(const float4*)(pb + (size_t)(t0 + t) * NPROJ + vcol + vq);
            vpl[t][vq + 0] = f.x; vpl[t][vq + 1] = f.y;
            vpl[t][vq + 2] = f.z; vpl[t][vq + 3] = f.w;
        }
        __syncthreads();

        // ---- P1b: lcp prefix (thread 0) + build Kc,Ks,Qc,Qs frags ----
        if (tid == 0) {
            float acc = ldl[0]; lcp[0] = acc;
            for (int t = 1; t < 32; t++) { acc += ldl[t]; lcp[t] = acc; }
        }
        {
            const int t = tid >> 3, k0 = (tid & 7) * 8;
            const float ft = (float)t;
            const float* rk = pb + (size_t)(t0 + t) * NPROJ + kcol + k0;
            const float* rq = pb + (size_t)(t0 + t) * NPROJ + qcol + k0;
            short8 kc8, ks8, qc8, qs8;
            #pragma unroll
            for (int j = 0; j < 8; j++) {
                float w = omgl[k0 + j];
                float ang = w * ft;
                float cth = cosf(ang), sth = sinf(ang);
                float kv = rk[j], qv = rq[j];
                kc8[j] = (short)f2bf(cth * kv); ks8[j] = (short)f2bf(sth * kv);
                qc8[j] = (short)f2bf(cth * qv); qs8[j] = (short)f2bf(sth * qv);
            }
            const int sI = k0 >> 4, ld_ = t + 32 * ((k0 >> 3) & 1);
            fragKc[sI][ld_] = kc8; fragKs[sI][ld_] = ks8;
            fragQc[sI][ld_] = qc8; fragQs[sI][ld_] = qs8;
        }
        __syncthreads();

        // ---- P2: GEMMs ----
        if (wid == 3) {             // S_kk -> M' (beta-folded, strict lower)
            f32x16 acc;
            #pragma unroll
            for (int i = 0; i < 16; i++) acc[i] = 0.0f;
            #pragma unroll
            for (int s = 0; s < 4; s++) {
                short8 a = fragKc[s][lane];
                acc = __builtin_amdgcn_mfma_f32_32x32x16_bf16(a, a, acc, 0, 0, 0);
                short8 bq = fragKs[s][lane];
                acc = __builtin_amdgcn_mfma_f32_32x32x16_bf16(bq, bq, acc, 0, 0, 0);
            }
            #pragma unroll
            for (int reg = 0; reg < 16; reg++) {
                int t = (reg & 3) + 8 * (reg >> 2) + 4 * hi;
                float val = 0.0f;
                if (l31 < t) val = bvec[t] * acc[reg] * exp2f(lcp[t] - lcp[l31]);
                Mm[t][l31] = val;
            }
        } else if (wid == 1) {      // S_qk -> N frag; T1q (acc kept)
            f32x16 acc;
            #pragma unroll
            for (int i = 0; i < 16; i++) acc[i] = 0.0f;
            #pragma unroll
            for (int s = 0; s < 4; s++) {
                acc = __builtin_amdgcn_mfma_f32_32x32x16_bf16(fragQc[s][lane], fragKc[s][lane], acc, 0, 0, 0);
                acc = __builtin_amdgcn_mfma_f32_32x32x16_bf16(fragQs[s][lane], fragKs[s][lane], acc, 0, 0, 0);
            }
            #pragma unroll
            for (int reg = 0; reg < 16; reg++) {
                int t = (reg & 3) + 8 * (reg >> 2) + 4 * hi;
                int ta = l31;
                float val = (ta <= t) ? acc[reg] * exp2f(lcp[t] - lcp[ta]) : 0.0f;
                ((ushort*)&fragN[ta >> 4][t + 32 * ((ta >> 3) & 1)])[ta & 7] = f2bf(val);
            }
            #pragma unroll
            for (int s = 0; s < 4; s++) {
                accT = __builtin_amdgcn_mfma_f32_32x32x16_bf16(fragQc[s][lane], fragZ[0][s][lane], accT, 0, 0, 0);
                accT = __builtin_amdgcn_mfma_f32_32x32x16_bf16(fragQc[s][lane], fragZ[1][s][lane], accT, 0, 0, 0);
                accT = __builtin_amdgcn_mfma_f32_32x32x16_bf16(fragQs[s][lane], fragZ[2][s][lane], accT, 0, 0, 0);
                accT = __builtin_amdgcn_mfma_f32_32x32x16_bf16(fragQs[s][lane], fragZ[3][s][lane], accT, 0, 0, 0);
            }
        } else if (wid == 2) {      // T1k -> LDS
            f32x16 acc;
            #pragma unroll
            for (int i = 0; i < 16; i++) acc[i] = 0.0f;
            #pragma unroll
            for (int s = 0; s < 4; s++) {
                acc = __builtin_amdgcn_mfma_f32_32x32x16_bf16(fragKc[s][lane], fragZ[0][s][lane], acc, 0, 0, 0);
                acc = __builtin_amdgcn_mfma_f32_32x32x16_bf16(fragKc[s][lane], fragZ[1][s][lane], acc, 0, 0, 0);
                acc = __builtin_amdgcn_mfma_f32_32x32x16_bf16(fragKs[s][lane], fragZ[2][s][lane], acc, 0, 0, 0);
                acc = __builtin_amdgcn_mfma_f32_32x32x16_bf16(fragKs[s][lane], fragZ[3][s][lane], acc, 0, 0, 0);
            }
            #pragma unroll
            for (int reg = 0; reg < 16; reg++) {
                int t = (reg & 3) + 8 * (reg >> 2) + 4 * hi;
                T1k[t][l31] = acc[reg] * exp2f(lcp[t]);
            }
        } else {                    // wid==0: W build (state-carry weights)
            for (int u = lane; u < 256; u += 64) {
                int k = u & 63, so = u >> 6;
                float w = omgl[k];
                float lcpE = lcp[31];
                short8 wr8, wi8;
                #pragma unroll
                for (int j = 0; j < 8; j++) {
                    int ta = so * 8 + j;
                    float pw = exp2f(lcpE - lcp[ta]);
                    float kv = pb[(size_t)(t0 + ta) * NPROJ + kcol + k];
                    float ang = w * (float)(31 - ta);
                    wr8[j] = (short)f2bf(pw * cosf(ang) * kv);
                    wi8[j] = (short)f2bf(pw * sinf(ang) * kv);
                }
                int tile = k >> 5, sm = so >> 1, ld_ = (k & 31) + 32 * (so & 1);
                fragW[0][tile][sm][ld_] = wr8;
                fragW[1][tile][sm][ld_] = wi8;
            }
        }
        __syncthreads();

        // ---- P3: forward substitution (wave 3) ----
        if (wid == 3) {
            float areg[32];
            #pragma unroll
            for (int i = 0; i < 32; i++) areg[i] = 0.0f;
            const int v = l31;
            #pragma unroll
            for (int t = 0; t < 32; t++) {
                float p = 0.0f;
                #pragma unroll
                for (int t4 = 0; t4 < t; t4 += 4) {
                    float4 m4 = *(const float4*)&Mm[t][t4];
                    p += m4.x * areg[t4] + m4.y * areg[t4 + 1]
                       + m4.z * areg[t4 + 2] + m4.w * areg[t4 + 3];
                }
                float at = bvec[t] * (vpl[t][v] - T1k[t][v]) - p;
                areg[t] = at;
                if (hi == ((t >> 3) & 1))
                    ((ushort*)&fragA[t >> 4][l31 + 32 * ((t >> 3) & 1)])[t & 7] = f2bf(at);
            }
        }
        __syncthreads();

        // ---- P4: reads + output (wave1) ; state update (waves 0,2) ----
        if (wid == 1) {
            #pragma unroll
            for (int reg = 0; reg < 16; reg++) {
                int t = (reg & 3) + 8 * (reg >> 2) + 4 * hi;
                accT[reg] *= exp2f(lcp[t]);
            }
            accT = __builtin_amdgcn_mfma_f32_32x32x16_bf16(fragN[0][lane], fragA[0][lane], accT, 0, 0, 0);
            accT = __builtin_amdgcn_mfma_f32_32x32x16_bf16(fragN[1][lane], fragA[1][lane], accT, 0, 0, 0);
            #pragma unroll
            for (int reg = 0; reg < 16; reg++) {
                int t = (reg & 3) + 8 * (reg >> 2) + 4 * hi;
                int v = l31;
                float g = pb[(size_t)(t0 + t) * NPROJ + gcol + v];
                atomicAdd(Acomb + ((size_t)(b * 128 + t0 + t)) * 512 + h * 64 + vh * 32 + v,
                          mw * accT[reg] * g);
            }
        } else if (wid == 0 || wid == 2) {
            const int tile = (wid == 0) ? 0 : 1;
            const int k = tile * 32 + l31;
            const int sIz = k >> 4, jz = k & 7, hbk = (k >> 3) & 1;
            const float cpE = exp2f(lcp[31]);
            const float c31v = c31x[k], s31v = s31x[k];
            const float cwv = cw64[k], swv = sw64[k];
            f32x16 aR, aI;
            #pragma unroll
            for (int reg = 0; reg < 16; reg++) {
                int v = (reg & 3) + 8 * (reg >> 2) + 4 * hi;
                int lf = v + 32 * hbk;
                float yr = bfu(((ushort*)&fragZ[0][sIz][lf])[jz]) + bfu(((ushort*)&fragZ[1][sIz][lf])[jz]);
                float yn = bfu(((ushort*)&fragZ[2][sIz][lf])[jz]) + bfu(((ushort*)&fragZ[3][sIz][lf])[jz]);
                float yi = -yn;
                aR[reg] = cpE * (c31v * yr - s31v * yi);
                aI[reg] = cpE * (s31v * yr + c31v * yi);
            }
            aR = __builtin_amdgcn_mfma_f32_32x32x16_bf16(fragA[0][lane], fragW[0][tile][0][lane], aR, 0, 0, 0);
            aR = __builtin_amdgcn_mfma_f32_32x32x16_bf16(fragA[1][lane], fragW[0][tile][1][lane], aR, 0, 0, 0);
            aI = __builtin_amdgcn_mfma_f32_32x32x16_bf16(fragA[0][lane], fragW[1][tile][0][lane], aI, 0, 0, 0);
            aI = __builtin_amdgcn_mfma_f32_32x32x16_bf16(fragA[1][lane], fragW[1][tile][1][lane], aI, 0, 0, 0);
            #pragma unroll
            for (int reg = 0; reg < 16; reg++) {
                int v = (reg & 3) + 8 * (reg >> 2) + 4 * hi;
                int lf = v + 32 * hbk;
                float zr = aR[reg], zi = aI[reg];
                float yrn = cwv * zr - swv * zi;    // pre-rotate: Y_new = Omega * Z_new
                float yin = swv * zr + cwv * zi;
                float nyi = -yin;
                ushort rh = f2bf(yrn);
                ushort ih = f2bf(nyi);
                ((ushort*)&fragZ[0][sIz][lf])[jz] = rh;
                ((ushort*)&fragZ[1][sIz][lf])[jz] = f2bf(yrn - bfu(rh));
                ((ushort*)&fragZ[2][sIz][lf])[jz] = ih;
                ((ushort*)&fragZ[3][sIz][lf])[jz] = f2bf(nyi - bfu(ih));
            }
        }
        __syncthreads();
    }
}

// ---------------- Kernel 4: output GEMM, depth-2 prefetch (NAMED regs) ----------------
__global__ __launch_bounds__(256, 2) void out_mfma(const float* __restrict__ Af,
        const ushort* __restrict__ BTb, float* __restrict__ C)
{
    __shared__ ushort sA[2][64][40];
    __shared__ ushort sB[2][64][40];
    const int n0 = blockIdx.x * 64, m0 = blockIdx.y * 64;
    const int tid = threadIdx.x;
    const int lane = tid & 63, w = tid >> 6;
    const int wm = w & 1, wn = w >> 1;
    const int l16 = lane & 15, quad = lane >> 4;
    const int srow = tid >> 2, skq = (tid & 3) * 8;
    const float* Ag = Af + (size_t)(m0 + srow) * 512 + skq;
    const ushort* Bg = BTb + (size_t)(n0 + srow) * 512 + skq;
    float4 fa0A = *(const float4*)Ag;
    float4 fa1A = *(const float4*)(Ag + 4);
    short8 rbA  = *(const short8*)Bg;
    float4 fa0B = *(const float4*)(Ag + 32);
    float4 fa1B = *(const float4*)(Ag + 36);
    short8 rbB  = *(const short8*)(Bg + 32);
    float4v acc00 = {0,0,0,0}, acc01 = {0,0,0,0}, acc10 = {0,0,0,0}, acc11 = {0,0,0,0};
    for (int kt = 0; kt < 16; kt += 2) {
        {
            short8 ra;
            ra[0]=f2bf(fa0A.x); ra[1]=f2bf(fa0A.y); ra[2]=f2bf(fa0A.z); ra[3]=f2bf(fa0A.w);
            ra[4]=f2bf(fa1A.x); ra[5]=f2bf(fa1A.y); ra[6]=f2bf(fa1A.z); ra[7]=f2bf(fa1A.w);
            *(short8*)&sA[0][srow][skq] = ra;
            *(short8*)&sB[0][srow][skq] = rbA;
        }
        __syncthreads();
        if (kt + 2 < 16) {
            fa0A = *(const float4*)(Ag + (kt + 2) * 32);
            fa1A = *(const float4*)(Ag + (kt + 2) * 32 + 4);
            rbA  = *(const short8*)(Bg + (kt + 2) * 32);
        }
        {
            short8 a0 = *(const short8*)&sA[0][wm * 32 + l16][quad * 8];
            short8 a1 = *(const short8*)&sA[0][wm * 32 + 16 + l16][quad * 8];
            short8 b0 = *(const short8*)&sB[0][wn * 32 + l16][quad * 8];
            short8 b1 = *(const short8*)&sB[0][wn * 32 + 16 + l16][quad * 8];
            acc00 = __builtin_amdgcn_mfma_f32_16x16x32_bf16(a0, b0, acc00, 0, 0, 0);
            acc01 = __builtin_amdgcn_mfma_f32_16x16x32_bf16(a0, b1, acc01, 0, 0, 0);
            acc10 = __builtin_amdgcn_mfma_f32_16x16x32_bf16(a1, b0, acc10, 0, 0, 0);
            acc11 = __builtin_amdgcn_mfma_f32_16x16x32_bf16(a1, b1, acc11, 0, 0, 0);
        }
        {
            short8 ra;
            ra[0]=f2bf(fa0B.x); ra[1]=f2bf(fa0B.y); ra[2]=f2bf(fa0B.z); ra[3]=f2bf(fa0B.w);
            ra[4]=f2bf(fa1B.x); ra[5]=f2bf(fa1B.y); ra[6]=f2bf(fa1B.z); ra[7]=f2bf(fa1B.w);
            *(short8*)&sA[1][srow][skq] = ra;
            *(short8*)&sB[1][srow][skq] = rbB;
        }
        __syncthreads();
        if (kt + 3 < 16) {
            fa0B = *(const float4*)(Ag + (kt + 3) * 32);
            fa1B = *(const float4*)(Ag + (kt + 3) * 32 + 4);
            rbB  = *(const short8*)(Bg + (kt + 3) * 32);
        }
        {
            short8 a0 = *(const short8*)&sA[1][wm * 32 + l16][quad * 8];
            short8 a1 = *(const short8*)&sA[1][wm * 32 + 16 + l16][quad * 8];
            short8 b0 = *(const short8*)&sB[1][wn * 32 + l16][quad * 8];
            short8 b1 = *(const short8*)&sB[1][wn * 32 + 16 + l16][quad * 8];
            acc00 = __builtin_amdgcn_mfma_f32_16x16x32_bf16(a0, b0, acc00, 0, 0, 0);
            acc01 = __builtin_amdgcn_mfma_f32_16x16x32_bf16(a0, b1, acc01, 0, 0, 0);
            acc10 = __builtin_amdgcn_mfma_f32_16x16x32_bf16(a1, b0, acc10, 0, 0, 0);
            acc11 = __builtin_amdgcn_mfma_f32_16x16x32_bf16(a1, b1, acc11, 0, 0, 0);
        }
    }
    const int colb = n0 + wn * 32 + l16;
    const int rowb = m0 + wm * 32 + quad * 4;
    #pragma unroll
    for (int r2 = 0; r2 < 4; r2++) {
        C[(size_t)(rowb + r2) * 1024 + colb] = acc00[r2];
        C[(size_t)(rowb + r2) * 1024 + colb + 16] = acc01[r2];
        C[(size_t)(rowb + 16 + r2) * 1024 + colb] = acc10[r2];
        C[(size_t)(rowb + 16 + r2) * 1024 + colb + 16] = acc11[r2];
    }
}

extern "C" void kernel_launch(void* const* d_in, const int* in_sizes, int n_in,
                              void* d_out, int out_size, void* d_ws, size_t ws_size,
                              hipStream_t stream) {
    const float* x   = (const float*)d_in[0];
    const float* Wq  = (const float*)d_in[1];
    const float* Wk  = (const float*)d_in[2];
    const float* Wv  = (const float*)d_in[3];
    const float* Wb  = (const float*)d_in[4];
    const float* Wtg = (const float*)d_in[5];
    const float* ml  = (const float*)d_in[6];
    const float* ldc = (const float*)d_in[7];
    const float* ols = (const float*)d_in[8];
    const float* Wg  = (const float*)d_in[9];
    const float* Wo  = (const float*)d_in[10];
    float* out = (float*)d_out;

    float* ws = (float*)d_ws;
    float* proj    = ws;                                 // 557056 f
    float* cosw    = proj + 256 * NPROJ;                 // 4096
    float* sinw    = cosw + 4096;                        // 4096
    float* rho     = sinw + 4096;                        // 64
    float* modew   = rho + 64;                           // 64
    ushort* xb     = (ushort*)(modew + 64);              // 262144 us = 131072 f
    ushort* wotb   = (ushort*)((float*)xb + 131072);     // 524288 us = 262144 f
    float*  Acomb  = (float*)wotb + 262144;              // 131072 f
    ushort* wtb    = (ushort*)(Acomb + 131072);          // 2228224 us = 1114112 f
    float*  omg    = (float*)(wtb + 2228224);            // 4096 f

    prep_kernel<<<784, 256, 0, stream>>>(x, Wq, Wk, Wv, Wb, Wtg, Wg, Wo,
                                         ml, ldc, ols, cosw, sinw, omg, rho, modew,
                                         xb, wtb, wotb, Acomb);
    proj_mfma<<<dim3(34, 4), 256, 0, stream>>>(xb, wtb, rho, proj);
    scan_kernel<<<256, 256, 0, stream>>>(proj, cosw, sinw, omg, modew, Acomb);
    out_mfma<<<dim3(16, 4), 256, 0, stream>>>(Acomb, wotb, out);
}

// Round 7
// 149.642 us; speedup vs baseline: 1.1986x; 1.1986x over previous
//
#include <hip/hip_runtime.h>
#include <math.h>

#define T_ 128
#define NPROJ 2176  // cols: [0,512)=Q [512,1024)=K [1024,1536)=V [1536,1600)=beta [1600,1664)=tg*rho [1664,2176)=gate
#define CH 32       // scan chunk

typedef __attribute__((ext_vector_type(8))) short short8;
typedef __attribute__((ext_vector_type(4))) float float4v;
typedef __attribute__((ext_vector_type(2))) float float2v;

__device__ __forceinline__ ushort f2bf(float x) {
    unsigned u = __float_as_uint(x);
    u += 0x7FFF + ((u >> 16) & 1);   // RNE
    return (ushort)(u >> 16);
}
// pack two fp32 -> one dword of 2 bf16 (round-to-nearest, no tie fix)
__device__ __forceinline__ unsigned pack_bf(float a, float b) {
    unsigned ua = (__float_as_uint(a) + 0x8000u) >> 16;
    unsigned ub = (__float_as_uint(b) + 0x8000u) & 0xffff0000u;
    return ua | ub;
}
__device__ __forceinline__ float bf_lo(unsigned w) { return __uint_as_float(w << 16); }
__device__ __forceinline__ float bf_hi(unsigned w) { return __uint_as_float(w & 0xffff0000u); }

// fused DPP butterfly add: compiles to a single v_add_f32_dpp
template<int CTRL>
__device__ __forceinline__ float dpp_add(float x) {
    int xi = __float_as_int(x);
    int yi = __builtin_amdgcn_update_dpp(xi, xi, CTRL, 0xF, 0xF, false);
    return x + __int_as_float(yi);
}
// xor16 allreduce-add within 32-lane groups.
// gfx950 v_permlane16_swap_b32: swaps alternating 16-lane rows between the two
// operands; with both operands = x, the two results sum to the row-pair total
// in every lane (VALU-only, no LDS round-trip). Fallback: ds_swizzle.
__device__ __forceinline__ float xr16_add(float x) {
#if __has_builtin(__builtin_amdgcn_permlane16_swap)
    unsigned xi = __float_as_uint(x);
    auto pr = __builtin_amdgcn_permlane16_swap(xi, xi, false, false);
    return __uint_as_float(pr[0]) + __uint_as_float(pr[1]);
#else
    int yi = __builtin_amdgcn_ds_swizzle(__float_as_int(x), 0x401F);
    return x + __int_as_float(yi);
#endif
}

// ---------------- Kernel 1: prep = params + x->bf16 + W/Wo transpose + Acomb zero -----
__global__ __launch_bounds__(256) void prep_kernel(
    const float* __restrict__ x,
    const float* __restrict__ Wq, const float* __restrict__ Wk,
    const float* __restrict__ Wv, const float* __restrict__ Wb,
    const float* __restrict__ Wtg, const float* __restrict__ Wg,
    const float* __restrict__ Wo,
    const float* __restrict__ mode_logits, const float* __restrict__ log_decay,
    const float* __restrict__ ols,
    float* __restrict__ cosw, float* __restrict__ sinw,
    float* __restrict__ rho, float* __restrict__ modew,
    ushort* __restrict__ xb, ushort* __restrict__ wtb, ushort* __restrict__ wotb,
    float* __restrict__ Acomb)
{
    __shared__ ushort tile[64][68];
    const int blk = blockIdx.x, tid = threadIdx.x;
    if (blk < 16) {
        int idx = blk * 256 + tid;
        if (idx >= 64 * 64) return;
        int t = idx >> 6;   // hr
        int k = idx & 63;
        int h = t >> 3;
        if (k == 0) {
            float ld = log_decay[t];
            rho[t] = 1.0f / (1.0f + expf(ld));  // exp(-softplus) == sigmoid(-x)
            float m = -1e30f;
            for (int i = 0; i < 8; i++) m = fmaxf(m, mode_logits[h * 8 + i]);
            float sum = 0.0f;
            for (int i = 0; i < 8; i++) sum += expf(mode_logits[h * 8 + i] - m);
            modew[t] = expf(mode_logits[t] - m) / sum;
        }
        float osc = expf(ols[t]);
        int p = k >> 1;
        float invf = expf(-((float)(2 * p) / 64.0f) * logf(10000.0f));
        float w = osc * invf;
        cosw[idx] = cosf(w);
        sinw[idx] = sinf(w);
        return;
    }
    if (blk < 80) {   // x convert
        int base = (blk - 16) * 4096 + tid * 16;
        float4 f0 = *(const float4*)&x[base];
        float4 f1 = *(const float4*)&x[base + 4];
        float4 f2 = *(const float4*)&x[base + 8];
        float4 f3 = *(const float4*)&x[base + 12];
        short8 o0, o1;
        o0[0]=f2bf(f0.x); o0[1]=f2bf(f0.y); o0[2]=f2bf(f0.z); o0[3]=f2bf(f0.w);
        o0[4]=f2bf(f1.x); o0[5]=f2bf(f1.y); o0[6]=f2bf(f1.z); o0[7]=f2bf(f1.w);
        o1[0]=f2bf(f2.x); o1[1]=f2bf(f2.y); o1[2]=f2bf(f2.z); o1[3]=f2bf(f2.w);
        o1[4]=f2bf(f3.x); o1[5]=f2bf(f3.y); o1[6]=f2bf(f3.z); o1[7]=f2bf(f3.w);
        *(short8*)&xb[base] = o0;
        *(short8*)&xb[base + 8] = o1;
        return;
    }
    if (blk >= 752) {  // zero Acomb
        int base = (blk - 752) * 4096 + tid * 16;
        float4 z = make_float4(0.f, 0.f, 0.f, 0.f);
        *(float4*)&Acomb[base] = z;
        *(float4*)&Acomb[base + 4] = z;
        *(float4*)&Acomb[base + 8] = z;
        *(float4*)&Acomb[base + 12] = z;
        return;
    }
    // transpose-convert
    const float* src; int ld, c0, n0, k0, ldd; ushort* dst;
    if (blk < 624) {
        int b3 = blk - 80; int nt = b3 >> 4, kt = b3 & 15;
        n0 = nt * 64; k0 = kt * 64;
        if (n0 < 512)       { src = Wq;  c0 = n0;        ld = 512; }
        else if (n0 < 1024) { src = Wk;  c0 = n0 - 512;  ld = 512; }
        else if (n0 < 1536) { src = Wv;  c0 = n0 - 1024; ld = 512; }
        else if (n0 < 1600) { src = Wb;  c0 = n0 - 1536; ld = 64;  }
        else if (n0 < 1664) { src = Wtg; c0 = n0 - 1600; ld = 64;  }
        else                { src = Wg;  c0 = n0 - 1664; ld = 512; }
        dst = wtb; ldd = 1024;
    } else {
        int b4 = blk - 624; int nt = b4 >> 3, kt = b4 & 7;
        n0 = nt * 64; k0 = kt * 64;
        src = Wo; c0 = n0; ld = 1024; dst = wotb; ldd = 512;
    }
    #pragma unroll
    for (int rep = 0; rep < 4; rep++) {
        int k = rep * 16 + (tid >> 4);
        int nc = (tid & 15) * 4;
        float4 f = *(const float4*)&src[(size_t)(k0 + k) * ld + c0 + nc];
        tile[nc + 0][k] = f2bf(f.x);
        tile[nc + 1][k] = f2bf(f.y);
        tile[nc + 2][k] = f2bf(f.z);
        tile[nc + 3][k] = f2bf(f.w);
    }
    __syncthreads();
    #pragma unroll
    for (int rep = 0; rep < 4; rep++) {
        int n = rep * 16 + (tid >> 4);
        int kc = (tid & 15) * 4;
        uint2 uu = *(const uint2*)&tile[n][kc];
        *(uint2*)&dst[(size_t)(n0 + n) * ldd + k0 + kc] = uu;
    }
}

// ---------------- Kernel 2: proj MFMA GEMM (depth-2 prefetch, NAMED regs) -------------
__global__ __launch_bounds__(256, 2) void proj_mfma(const ushort* __restrict__ Ab,
        const ushort* __restrict__ BTb, const float* __restrict__ rho,
        float* __restrict__ proj)
{
    __shared__ ushort sA[2][64][40];
    __shared__ ushort sB[2][64][40];
    const int n0 = blockIdx.x * 64, m0 = blockIdx.y * 64;
    const int tid = threadIdx.x;
    const int lane = tid & 63, w = tid >> 6;
    const int wm = w & 1, wn = w >> 1;
    const int l16 = lane & 15, quad = lane >> 4;
    const int srow = tid >> 2, skq = (tid & 3) * 8;
    const ushort* Ag = Ab + (size_t)(m0 + srow) * 1024 + skq;
    const ushort* Bg = BTb + (size_t)(n0 + srow) * 1024 + skq;
    short8 raA = *(const short8*)Ag;
    short8 rbA = *(const short8*)Bg;
    short8 raB = *(const short8*)(Ag + 32);
    short8 rbB = *(const short8*)(Bg + 32);
    float4v acc00 = {0,0,0,0}, acc01 = {0,0,0,0}, acc10 = {0,0,0,0}, acc11 = {0,0,0,0};
    for (int kt = 0; kt < 32; kt += 2) {
        *(short8*)&sA[0][srow][skq] = raA;
        *(short8*)&sB[0][srow][skq] = rbA;
        __syncthreads();
        if (kt + 2 < 32) {
            raA = *(const short8*)(Ag + (kt + 2) * 32);
            rbA = *(const short8*)(Bg + (kt + 2) * 32);
        }
        {
            short8 a0 = *(const short8*)&sA[0][wm * 32 + l16][quad * 8];
            short8 a1 = *(const short8*)&sA[0][wm * 32 + 16 + l16][quad * 8];
            short8 b0 = *(const short8*)&sB[0][wn * 32 + l16][quad * 8];
            short8 b1 = *(const short8*)&sB[0][wn * 32 + 16 + l16][quad * 8];
            acc00 = __builtin_amdgcn_mfma_f32_16x16x32_bf16(a0, b0, acc00, 0, 0, 0);
            acc01 = __builtin_amdgcn_mfma_f32_16x16x32_bf16(a0, b1, acc01, 0, 0, 0);
            acc10 = __builtin_amdgcn_mfma_f32_16x16x32_bf16(a1, b0, acc10, 0, 0, 0);
            acc11 = __builtin_amdgcn_mfma_f32_16x16x32_bf16(a1, b1, acc11, 0, 0, 0);
        }
        *(short8*)&sA[1][srow][skq] = raB;
        *(short8*)&sB[1][srow][skq] = rbB;
        __syncthreads();
        if (kt + 3 < 32) {
            raB = *(const short8*)(Ag + (kt + 3) * 32);
            rbB = *(const short8*)(Bg + (kt + 3) * 32);
        }
        {
            short8 a0 = *(const short8*)&sA[1][wm * 32 + l16][quad * 8];
            short8 a1 = *(const short8*)&sA[1][wm * 32 + 16 + l16][quad * 8];
            short8 b0 = *(const short8*)&sB[1][wn * 32 + l16][quad * 8];
            short8 b1 = *(const short8*)&sB[1][wn * 32 + 16 + l16][quad * 8];
            acc00 = __builtin_amdgcn_mfma_f32_16x16x32_bf16(a0, b0, acc00, 0, 0, 0);
            acc01 = __builtin_amdgcn_mfma_f32_16x16x32_bf16(a0, b1, acc01, 0, 0, 0);
            acc10 = __builtin_amdgcn_mfma_f32_16x16x32_bf16(a1, b0, acc10, 0, 0, 0);
            acc11 = __builtin_amdgcn_mfma_f32_16x16x32_bf16(a1, b1, acc11, 0, 0, 0);
        }
    }
    const bool sig = (n0 >= 1536);
    float m0c = 1.0f, m1c = 1.0f;
    if (n0 == 1600) {
        m0c = rho[wn * 32 + l16];
        m1c = rho[wn * 32 + l16 + 16];
    }
    const int colb = n0 + wn * 32 + l16;
    const int rowb = m0 + wm * 32 + quad * 4;
    #pragma unroll
    for (int r2 = 0; r2 < 4; r2++) {
        float v00 = acc00[r2], v01 = acc01[r2], v10 = acc10[r2], v11 = acc11[r2];
        if (sig) {
            v00 = m0c / (1.0f + expf(-v00));
            v01 = m1c / (1.0f + expf(-v01));
            v10 = m0c / (1.0f + expf(-v10));
            v11 = m1c / (1.0f + expf(-v11));
        }
        proj[(size_t)(rowb + r2) * NPROJ + colb] = v00;
        proj[(size_t)(rowb + r2) * NPROJ + colb + 16] = v01;
        proj[(size_t)(rowb + 16 + r2) * NPROJ + colb] = v10;
        proj[(size_t)(rowb + 16 + r2) * NPROJ + colb + 16] = v11;
    }
}

// ---------------- Kernel 3: scan — interleaved k|q LDS (1 b64/step), permlane reduce --
// grid 512 = b(2) x hr(64) x s(4); block 512: vl = tid>>5 (16 v), kl = tid&31 (2 k each)
// LDS qks row: dword 2p = k-pair p (bf16x2), dword 2p+1 = q-pair p
// vg = {beta*v, mw*gate}; sc4 = {beta*d, d, kq}
__global__ __launch_bounds__(512, 4) void scan_kernel(const float* __restrict__ proj,
        const float* __restrict__ cosw, const float* __restrict__ sinw,
        const float* __restrict__ modew, float* __restrict__ Acomb)
{
    __shared__ unsigned qks[2][CH][64];  // 16 KB
    __shared__ float2 vg[2][CH][16];     //  8 KB
    __shared__ float sc4[2][CH][4];      //  1 KB
    __shared__ float obuf[CH][16];       //  2 KB

    const int bi = blockIdx.x;
    const int s  = bi & 3;
    const int hr = (bi >> 2) & 63;
    const int b  = bi >> 8;
    const int h = hr >> 3, r = hr & 7;
    const int tid = threadIdx.x;
    const int vl = tid >> 5;             // 0..15
    const int kl = tid & 31;             // 0..31, low 5 lane bits

    float2v cw0, sw0;
    cw0.x = cosw[hr * 64 + kl * 2 + 0]; cw0.y = cosw[hr * 64 + kl * 2 + 1];
    sw0.x = sinw[hr * 64 + kl * 2 + 0]; sw0.y = sinw[hr * 64 + kl * 2 + 1];
    const float mw = modew[hr];
    float2v sr0 = {0,0}, si0 = {0,0};

    const float* pb = proj + (size_t)b * T_ * NPROJ;
    const int qbase = h * 64;
    const int kbase = 512 + h * 64;
    const int vbase = 1024 + h * 64 + s * 16;
    const int gbase = 1664 + h * 64 + s * 16;
    const int boff  = 1536 + h * 8 + r;
    const int goff  = 1600 + h * 8 + r;

    // stage chunk 0 directly global->LDS (fp32 -> packed bf16, interleaved k|q)
    {
        #pragma unroll
        for (int rep = 0; rep < 2; rep++) {
            int idx = rep * 512 + tid;
            int t = idx >> 5, sub = idx & 31;
            const float* row = pb + (size_t)t * NPROJ;
            float4 f = *(const float4*)(row + (sub < 16 ? kbase + sub * 4
                                                        : qbase + (sub - 16) * 4));
            unsigned lo = pack_bf(f.x, f.y), hi2 = pack_bf(f.z, f.w);
            int bd_ = (sub < 16) ? 4 * sub : 4 * (sub - 16) + 1;
            qks[0][t][bd_]     = lo;
            qks[0][t][bd_ + 2] = hi2;
        }
        {
            int t = tid >> 4, v2 = tid & 15;
            const float* row = pb + (size_t)t * NPROJ;
            float be = row[boff];
            vg[0][t][v2] = make_float2(be * row[vbase + v2], mw * row[gbase + v2]);
        }
        if (tid < CH) {
            const float* row = pb + (size_t)tid * NPROJ;
            float be = row[boff], dd = row[goff];
            sc4[0][tid][0] = be * dd;
            sc4[0][tid][1] = dd;
        }
    }
    __syncthreads();

    float* dstb = Acomb + ((size_t)b * 128) * 512 + h * 64 + s * 16;

    for (int c = 0; c < T_ / CH; c++) {
        const int cb = c & 1, nb = cb ^ 1;
        const bool have = (c + 1 < T_ / CH);

        // --- global prefetch chunk c+1 into registers ---
        float4 g_qk0, g_qk1; float g_v, g_g, g_be, g_be2 = 0.0f, g_dd = 0.0f;
        if (have) {
            const int t0 = (c + 1) * CH;
            {
                int idx = tid;
                int t = idx >> 5, sub = idx & 31;
                const float* row = pb + (size_t)(t0 + t) * NPROJ;
                g_qk0 = *(const float4*)(row + (sub < 16 ? kbase + sub * 4
                                                         : qbase + (sub - 16) * 4));
            }
            {
                int idx = 512 + tid;
                int t = idx >> 5, sub = idx & 31;
                const float* row = pb + (size_t)(t0 + t) * NPROJ;
                g_qk1 = *(const float4*)(row + (sub < 16 ? kbase + sub * 4
                                                         : qbase + (sub - 16) * 4));
            }
            {
                int t = tid >> 4, v2 = tid & 15;
                const float* row = pb + (size_t)(t0 + t) * NPROJ;
                g_v  = row[vbase + v2];
                g_g  = row[gbase + v2];
                g_be = row[boff];
            }
            if (tid < CH) {
                const float* row = pb + (size_t)(t0 + tid) * NPROJ;
                g_be2 = row[boff];
                g_dd  = row[goff];
            }
        }

        // --- hoisted kq_t for this chunk (16 lanes per t, one b128 each) ---
        {
            int t = tid >> 4, j = tid & 15;
            uint4 u = *(const uint4*)&qks[cb][t][4 * j];
            float p = bf_lo(u.x) * bf_lo(u.y) + bf_hi(u.x) * bf_hi(u.y)
                    + bf_lo(u.z) * bf_lo(u.w) + bf_hi(u.z) * bf_hi(u.w);
            p = dpp_add<0xB1>(p);   // xor1
            p = dpp_add<0x4E>(p);   // xor2
            p = dpp_add<0x141>(p);  // xor4 (half-mirror, valid on quad-uniform)
            p = dpp_add<0x140>(p);  // xor8 (mirror, valid on 8-uniform)
            if (j == 0) sc4[cb][t][2] = p;
        }
        // --- flush previous chunk's outputs ---
        if (c > 0) {
            int t = tid >> 4, v2 = tid & 15;
            atomicAdd(dstb + (size_t)((c - 1) * CH + t) * 512 + v2, obuf[t][v2]);
        }
        __syncthreads();

        // --- 32 steps; per step: 1 ds_read_b64 (k|q pair) + sv b128 + vg b64 ---
        const float2* vgb = &vg[cb][0][0];
        const float4* svb = (const float4*)&sc4[cb][0][0];
        const unsigned* qd_base = &qks[cb][0][0];

        uint2 kq2 = *(const uint2*)&qd_base[2 * kl];
        float4 sv = svb[0];
        float2 vgv = vgb[vl];
        #pragma unroll
        for (int t = 0; t < CH; t++) {
            uint2 kq2_n; float4 sv_n; float2 vg_n;
            if (t + 1 < CH) {
                kq2_n = *(const uint2*)&qd_base[(t + 1) * 64 + 2 * kl];
                sv_n = svb[t + 1];
                vg_n = vgb[(t + 1) * 16 + vl];
            }

            float2v k0; k0.x = bf_lo(kq2.x); k0.y = bf_hi(kq2.x);
            float2v q0; q0.x = bf_lo(kq2.y); q0.y = bf_hi(kq2.y);

            float2v t1 = cw0 * sr0 - sw0 * si0;
            float2v u1 = sw0 * sr0 + cw0 * si0;
            float2v pk2 = t1 * k0;
            float2v pq2 = t1 * q0;
            float pk = pk2.x + pk2.y;
            float pq = pq2.x + pq2.y;
            pk = dpp_add<0xB1>(pk);  pq = dpp_add<0xB1>(pq);   // xor1
            pk = dpp_add<0x4E>(pk);  pq = dpp_add<0x4E>(pq);   // xor2
            pk = dpp_add<0x141>(pk); pq = dpp_add<0x141>(pq);  // xor4
            pk = dpp_add<0x140>(pk); pq = dpp_add<0x140>(pq);  // xor8
            pk = xr16_add(pk);       pq = xr16_add(pq);        // xor16 (VALU permlane)

            const float d = sv.y;
            float2v d2; d2.x = d; d2.y = d;
            float2v rr0 = d2 * t1;
            si0 = d2 * u1;
            const float sc = vgv.x - sv.x * pk;       // beta*v - (beta*d)*pk
            float2v sc2; sc2.x = sc; sc2.y = sc;
            sr0 = rr0 + sc2 * k0;
            const float rp = d * pq + sc * sv.z;      // = sum(sr_new * q)
            if (kl == 0) obuf[t][vl] = rp * vgv.y;    // * mw*gate (pre-folded)

            kq2 = kq2_n; sv = sv_n; vgv = vg_n;
        }

        // --- write staged registers into the other LDS buffer ---
        if (have) {
            {
                int idx = tid;
                int t = idx >> 5, sub = idx & 31;
                unsigned lo = pack_bf(g_qk0.x, g_qk0.y), hi2 = pack_bf(g_qk0.z, g_qk0.w);
                int bd_ = (sub < 16) ? 4 * sub : 4 * (sub - 16) + 1;
                qks[nb][t][bd_]     = lo;
                qks[nb][t][bd_ + 2] = hi2;
            }
            {
                int idx = 512 + tid;
                int t = idx >> 5, sub = idx & 31;
                unsigned lo = pack_bf(g_qk1.x, g_qk1.y), hi2 = pack_bf(g_qk1.z, g_qk1.w);
                int bd_ = (sub < 16) ? 4 * sub : 4 * (sub - 16) + 1;
                qks[nb][t][bd_]     = lo;
                qks[nb][t][bd_ + 2] = hi2;
            }
            {
                int t = tid >> 4, v2 = tid & 15;
                vg[nb][t][v2] = make_float2(g_be * g_v, mw * g_g);
            }
            if (tid < CH) {
                sc4[nb][tid][0] = g_be2 * g_dd;
                sc4[nb][tid][1] = g_dd;
            }
        }
        __syncthreads();
    }
    // final flush
    {
        int t = tid >> 4, v2 = tid & 15;
        atomicAdd(dstb + (size_t)(3 * CH + t) * 512 + v2, obuf[t][v2]);
    }
}

// ---------------- Kernel 4: output GEMM, depth-2 prefetch (NAMED regs) ----------------
__global__ __launch_bounds__(256, 2) void out_mfma(const float* __restrict__ Af,
        const ushort* __restrict__ BTb, float* __restrict__ C)
{
    __shared__ ushort sA[2][64][40];
    __shared__ ushort sB[2][64][40];
    const int n0 = blockIdx.x * 64, m0 = blockIdx.y * 64;
    const int tid = threadIdx.x;
    const int lane = tid & 63, w = tid >> 6;
    const int wm = w & 1, wn = w >> 1;
    const int l16 = lane & 15, quad = lane >> 4;
    const int srow = tid >> 2, skq = (tid & 3) * 8;
    const float* Ag = Af + (size_t)(m0 + srow) * 512 + skq;
    const ushort* Bg = BTb + (size_t)(n0 + srow) * 512 + skq;
    float4 fa0A = *(const float4*)Ag;
    float4 fa1A = *(const float4*)(Ag + 4);
    short8 rbA  = *(const short8*)Bg;
    float4 fa0B = *(const float4*)(Ag + 32);
    float4 fa1B = *(const float4*)(Ag + 36);
    short8 rbB  = *(const short8*)(Bg + 32);
    float4v acc00 = {0,0,0,0}, acc01 = {0,0,0,0}, acc10 = {0,0,0,0}, acc11 = {0,0,0,0};
    for (int kt = 0; kt < 16; kt += 2) {
        {
            short8 ra;
            ra[0]=f2bf(fa0A.x); ra[1]=f2bf(fa0A.y); ra[2]=f2bf(fa0A.z); ra[3]=f2bf(fa0A.w);
            ra[4]=f2bf(fa1A.x); ra[5]=f2bf(fa1A.y); ra[6]=f2bf(fa1A.z); ra[7]=f2bf(fa1A.w);
            *(short8*)&sA[0][srow][skq] = ra;
            *(short8*)&sB[0][srow][skq] = rbA;
        }
        __syncthreads();
        if (kt + 2 < 16) {
            fa0A = *(const float4*)(Ag + (kt + 2) * 32);
            fa1A = *(const float4*)(Ag + (kt + 2) * 32 + 4);
            rbA  = *(const short8*)(Bg + (kt + 2) * 32);
        }
        {
            short8 a0 = *(const short8*)&sA[0][wm * 32 + l16][quad * 8];
            short8 a1 = *(const short8*)&sA[0][wm * 32 + 16 + l16][quad * 8];
            short8 b0 = *(const short8*)&sB[0][wn * 32 + l16][quad * 8];
            short8 b1 = *(const short8*)&sB[0][wn * 32 + 16 + l16][quad * 8];
            acc00 = __builtin_amdgcn_mfma_f32_16x16x32_bf16(a0, b0, acc00, 0, 0, 0);
            acc01 = __builtin_amdgcn_mfma_f32_16x16x32_bf16(a0, b1, acc01, 0, 0, 0);
            acc10 = __builtin_amdgcn_mfma_f32_16x16x32_bf16(a1, b0, acc10, 0, 0, 0);
            acc11 = __builtin_amdgcn_mfma_f32_16x16x32_bf16(a1, b1, acc11, 0, 0, 0);
        }
        {
            short8 ra;
            ra[0]=f2bf(fa0B.x); ra[1]=f2bf(fa0B.y); ra[2]=f2bf(fa0B.z); ra[3]=f2bf(fa0B.w);
            ra[4]=f2bf(fa1B.x); ra[5]=f2bf(fa1B.y); ra[6]=f2bf(fa1B.z); ra[7]=f2bf(fa1B.w);
            *(short8*)&sA[1][srow][skq] = ra;
            *(short8*)&sB[1][srow][skq] = rbB;
        }
        __syncthreads();
        if (kt + 3 < 16) {
            fa0B = *(const float4*)(Ag + (kt + 3) * 32);
            fa1B = *(const float4*)(Ag + (kt + 3) * 32 + 4);
            rbB  = *(const short8*)(Bg + (kt + 3) * 32);
        }
        {
            short8 a0 = *(const short8*)&sA[1][wm * 32 + l16][quad * 8];
            short8 a1 = *(const short8*)&sA[1][wm * 32 + 16 + l16][quad * 8];
            short8 b0 = *(const short8*)&sB[1][wn * 32 + l16][quad * 8];
            short8 b1 = *(const short8*)&sB[1][wn * 32 + 16 + l16][quad * 8];
            acc00 = __builtin_amdgcn_mfma_f32_16x16x32_bf16(a0, b0, acc00, 0, 0, 0);
            acc01 = __builtin_amdgcn_mfma_f32_16x16x32_bf16(a0, b1, acc01, 0, 0, 0);
            acc10 = __builtin_amdgcn_mfma_f32_16x16x32_bf16(a1, b0, acc10, 0, 0, 0);
            acc11 = __builtin_amdgcn_mfma_f32_16x16x32_bf16(a1, b1, acc11, 0, 0, 0);
        }
    }
    const int colb = n0 + wn * 32 + l16;
    const int rowb = m0 + wm * 32 + quad * 4;
    #pragma unroll
    for (int r2 = 0; r2 < 4; r2++) {
        C[(size_t)(rowb + r2) * 1024 + colb] = acc00[r2];
        C[(size_t)(rowb + r2) * 1024 + colb + 16] = acc01[r2];
        C[(size_t)(rowb + 16 + r2) * 1024 + colb] = acc10[r2];
        C[(size_t)(rowb + 16 + r2) * 1024 + colb + 16] = acc11[r2];
    }
}

extern "C" void kernel_launch(void* const* d_in, const int* in_sizes, int n_in,
                              void* d_out, int out_size, void* d_ws, size_t ws_size,
                              hipStream_t stream) {
    const float* x   = (const float*)d_in[0];
    const float* Wq  = (const float*)d_in[1];
    const float* Wk  = (const float*)d_in[2];
    const float* Wv  = (const float*)d_in[3];
    const float* Wb  = (const float*)d_in[4];
    const float* Wtg = (const float*)d_in[5];
    const float* ml  = (const float*)d_in[6];
    const float* ldc = (const float*)d_in[7];
    const float* ols = (const float*)d_in[8];
    const float* Wg  = (const float*)d_in[9];
    const float* Wo  = (const float*)d_in[10];
    float* out = (float*)d_out;

    float* ws = (float*)d_ws;
    float* proj    = ws;                                 // 557056 f
    float* cosw    = proj + 256 * NPROJ;                 // 4096
    float* sinw    = cosw + 4096;                        // 4096
    float* rho     = sinw + 4096;                        // 64
    float* modew   = rho + 64;                           // 64
    ushort* xb     = (ushort*)(modew + 64);              // 262144 us = 131072 f
    ushort* wotb   = (ushort*)((float*)xb + 131072);     // 524288 us = 262144 f
    float*  Acomb  = (float*)wotb + 262144;              // 131072 f
    ushort* wtb    = (ushort*)(Acomb + 131072);          // 2228224 us = 1114112 f

    prep_kernel<<<784, 256, 0, stream>>>(x, Wq, Wk, Wv, Wb, Wtg, Wg, Wo,
                                         ml, ldc, ols, cosw, sinw, rho, modew,
                                         xb, wtb, wotb, Acomb);
    proj_mfma<<<dim3(34, 4), 256, 0, stream>>>(xb, wtb, rho, proj);
    scan_kernel<<<512, 512, 0, stream>>>(proj, cosw, sinw, modew, Acomb);
    out_mfma<<<dim3(16, 4), 256, 0, stream>>>(Acomb, wotb, out);
}

// Round 8
// 135.914 us; speedup vs baseline: 1.3197x; 1.1010x over previous
//
#include <hip/hip_runtime.h>
#include <math.h>

#define T_ 128
#define NPROJ 2176  // cols: [0,512)=Q [512,1024)=K [1024,1536)=V [1536,1600)=beta [1600,1664)=tg*rho [1664,2176)=gate
#define CH 32       // scan chunk

typedef __attribute__((ext_vector_type(8))) short short8;
typedef __attribute__((ext_vector_type(4))) float float4v;
typedef __attribute__((ext_vector_type(2))) float float2v;

__device__ __forceinline__ ushort f2bf(float x) {
    unsigned u = __float_as_uint(x);
    u += 0x7FFF + ((u >> 16) & 1);   // RNE
    return (ushort)(u >> 16);
}
// pack two fp32 -> one dword of 2 bf16 (round-to-nearest, no tie fix)
__device__ __forceinline__ unsigned pack_bf(float a, float b) {
    unsigned ua = (__float_as_uint(a) + 0x8000u) >> 16;
    unsigned ub = (__float_as_uint(b) + 0x8000u) & 0xffff0000u;
    return ua | ub;
}
__device__ __forceinline__ float bf_lo(unsigned w) { return __uint_as_float(w << 16); }
__device__ __forceinline__ float bf_hi(unsigned w) { return __uint_as_float(w & 0xffff0000u); }

// fused DPP butterfly add: compiles to a single v_add_f32_dpp
template<int CTRL>
__device__ __forceinline__ float dpp_add(float x) {
    int xi = __float_as_int(x);
    int yi = __builtin_amdgcn_update_dpp(xi, xi, CTRL, 0xF, 0xF, false);
    return x + __int_as_float(yi);
}

// ---------------- Kernel 1: prep = params + x->bf16 + W/Wo transpose + Acomb zero -----
__global__ __launch_bounds__(256) void prep_kernel(
    const float* __restrict__ x,
    const float* __restrict__ Wq, const float* __restrict__ Wk,
    const float* __restrict__ Wv, const float* __restrict__ Wb,
    const float* __restrict__ Wtg, const float* __restrict__ Wg,
    const float* __restrict__ Wo,
    const float* __restrict__ mode_logits, const float* __restrict__ log_decay,
    const float* __restrict__ ols,
    float* __restrict__ cosw, float* __restrict__ sinw,
    float* __restrict__ rho, float* __restrict__ modew,
    ushort* __restrict__ xb, ushort* __restrict__ wtb, ushort* __restrict__ wotb,
    float* __restrict__ Acomb)
{
    __shared__ ushort tile[64][68];
    const int blk = blockIdx.x, tid = threadIdx.x;
    if (blk < 16) {
        int idx = blk * 256 + tid;
        if (idx >= 64 * 64) return;
        int t = idx >> 6;   // hr
        int k = idx & 63;
        int h = t >> 3;
        if (k == 0) {
            float ld = log_decay[t];
            rho[t] = 1.0f / (1.0f + expf(ld));  // exp(-softplus) == sigmoid(-x)
            float m = -1e30f;
            for (int i = 0; i < 8; i++) m = fmaxf(m, mode_logits[h * 8 + i]);
            float sum = 0.0f;
            for (int i = 0; i < 8; i++) sum += expf(mode_logits[h * 8 + i] - m);
            modew[t] = expf(mode_logits[t] - m) / sum;
        }
        float osc = expf(ols[t]);
        int p = k >> 1;
        float invf = expf(-((float)(2 * p) / 64.0f) * logf(10000.0f));
        float w = osc * invf;
        cosw[idx] = cosf(w);
        sinw[idx] = sinf(w);
        return;
    }
    if (blk < 80) {   // x convert
        int base = (blk - 16) * 4096 + tid * 16;
        float4 f0 = *(const float4*)&x[base];
        float4 f1 = *(const float4*)&x[base + 4];
        float4 f2 = *(const float4*)&x[base + 8];
        float4 f3 = *(const float4*)&x[base + 12];
        short8 o0, o1;
        o0[0]=f2bf(f0.x); o0[1]=f2bf(f0.y); o0[2]=f2bf(f0.z); o0[3]=f2bf(f0.w);
        o0[4]=f2bf(f1.x); o0[5]=f2bf(f1.y); o0[6]=f2bf(f1.z); o0[7]=f2bf(f1.w);
        o1[0]=f2bf(f2.x); o1[1]=f2bf(f2.y); o1[2]=f2bf(f2.z); o1[3]=f2bf(f2.w);
        o1[4]=f2bf(f3.x); o1[5]=f2bf(f3.y); o1[6]=f2bf(f3.z); o1[7]=f2bf(f3.w);
        *(short8*)&xb[base] = o0;
        *(short8*)&xb[base + 8] = o1;
        return;
    }
    if (blk >= 752) {  // zero Acomb
        int base = (blk - 752) * 4096 + tid * 16;
        float4 z = make_float4(0.f, 0.f, 0.f, 0.f);
        *(float4*)&Acomb[base] = z;
        *(float4*)&Acomb[base + 4] = z;
        *(float4*)&Acomb[base + 8] = z;
        *(float4*)&Acomb[base + 12] = z;
        return;
    }
    // transpose-convert
    const float* src; int ld, c0, n0, k0, ldd; ushort* dst;
    if (blk < 624) {
        int b3 = blk - 80; int nt = b3 >> 4, kt = b3 & 15;
        n0 = nt * 64; k0 = kt * 64;
        if (n0 < 512)       { src = Wq;  c0 = n0;        ld = 512; }
        else if (n0 < 1024) { src = Wk;  c0 = n0 - 512;  ld = 512; }
        else if (n0 < 1536) { src = Wv;  c0 = n0 - 1024; ld = 512; }
        else if (n0 < 1600) { src = Wb;  c0 = n0 - 1536; ld = 64;  }
        else if (n0 < 1664) { src = Wtg; c0 = n0 - 1600; ld = 64;  }
        else                { src = Wg;  c0 = n0 - 1664; ld = 512; }
        dst = wtb; ldd = 1024;
    } else {
        int b4 = blk - 624; int nt = b4 >> 3, kt = b4 & 7;
        n0 = nt * 64; k0 = kt * 64;
        src = Wo; c0 = n0; ld = 1024; dst = wotb; ldd = 512;
    }
    #pragma unroll
    for (int rep = 0; rep < 4; rep++) {
        int k = rep * 16 + (tid >> 4);
        int nc = (tid & 15) * 4;
        float4 f = *(const float4*)&src[(size_t)(k0 + k) * ld + c0 + nc];
        tile[nc + 0][k] = f2bf(f.x);
        tile[nc + 1][k] = f2bf(f.y);
        tile[nc + 2][k] = f2bf(f.z);
        tile[nc + 3][k] = f2bf(f.w);
    }
    __syncthreads();
    #pragma unroll
    for (int rep = 0; rep < 4; rep++) {
        int n = rep * 16 + (tid >> 4);
        int kc = (tid & 15) * 4;
        uint2 uu = *(const uint2*)&tile[n][kc];
        *(uint2*)&dst[(size_t)(n0 + n) * ldd + k0 + kc] = uu;
    }
}

// ---------------- Kernel 2: proj MFMA GEMM (depth-2 prefetch, NAMED regs) -------------
__global__ __launch_bounds__(256, 2) void proj_mfma(const ushort* __restrict__ Ab,
        const ushort* __restrict__ BTb, const float* __restrict__ rho,
        float* __restrict__ proj)
{
    __shared__ ushort sA[2][64][40];
    __shared__ ushort sB[2][64][40];
    const int n0 = blockIdx.x * 64, m0 = blockIdx.y * 64;
    const int tid = threadIdx.x;
    const int lane = tid & 63, w = tid >> 6;
    const int wm = w & 1, wn = w >> 1;
    const int l16 = lane & 15, quad = lane >> 4;
    const int srow = tid >> 2, skq = (tid & 3) * 8;
    const ushort* Ag = Ab + (size_t)(m0 + srow) * 1024 + skq;
    const ushort* Bg = BTb + (size_t)(n0 + srow) * 1024 + skq;
    short8 raA = *(const short8*)Ag;
    short8 rbA = *(const short8*)Bg;
    short8 raB = *(const short8*)(Ag + 32);
    short8 rbB = *(const short8*)(Bg + 32);
    float4v acc00 = {0,0,0,0}, acc01 = {0,0,0,0}, acc10 = {0,0,0,0}, acc11 = {0,0,0,0};
    for (int kt = 0; kt < 32; kt += 2) {
        *(short8*)&sA[0][srow][skq] = raA;
        *(short8*)&sB[0][srow][skq] = rbA;
        __syncthreads();
        if (kt + 2 < 32) {
            raA = *(const short8*)(Ag + (kt + 2) * 32);
            rbA = *(const short8*)(Bg + (kt + 2) * 32);
        }
        {
            short8 a0 = *(const short8*)&sA[0][wm * 32 + l16][quad * 8];
            short8 a1 = *(const short8*)&sA[0][wm * 32 + 16 + l16][quad * 8];
            short8 b0 = *(const short8*)&sB[0][wn * 32 + l16][quad * 8];
            short8 b1 = *(const short8*)&sB[0][wn * 32 + 16 + l16][quad * 8];
            acc00 = __builtin_amdgcn_mfma_f32_16x16x32_bf16(a0, b0, acc00, 0, 0, 0);
            acc01 = __builtin_amdgcn_mfma_f32_16x16x32_bf16(a0, b1, acc01, 0, 0, 0);
            acc10 = __builtin_amdgcn_mfma_f32_16x16x32_bf16(a1, b0, acc10, 0, 0, 0);
            acc11 = __builtin_amdgcn_mfma_f32_16x16x32_bf16(a1, b1, acc11, 0, 0, 0);
        }
        *(short8*)&sA[1][srow][skq] = raB;
        *(short8*)&sB[1][srow][skq] = rbB;
        __syncthreads();
        if (kt + 3 < 32) {
            raB = *(const short8*)(Ag + (kt + 3) * 32);
            rbB = *(const short8*)(Bg + (kt + 3) * 32);
        }
        {
            short8 a0 = *(const short8*)&sA[1][wm * 32 + l16][quad * 8];
            short8 a1 = *(const short8*)&sA[1][wm * 32 + 16 + l16][quad * 8];
            short8 b0 = *(const short8*)&sB[1][wn * 32 + l16][quad * 8];
            short8 b1 = *(const short8*)&sB[1][wn * 32 + 16 + l16][quad * 8];
            acc00 = __builtin_amdgcn_mfma_f32_16x16x32_bf16(a0, b0, acc00, 0, 0, 0);
            acc01 = __builtin_amdgcn_mfma_f32_16x16x32_bf16(a0, b1, acc01, 0, 0, 0);
            acc10 = __builtin_amdgcn_mfma_f32_16x16x32_bf16(a1, b0, acc10, 0, 0, 0);
            acc11 = __builtin_amdgcn_mfma_f32_16x16x32_bf16(a1, b1, acc11, 0, 0, 0);
        }
    }
    const bool sig = (n0 >= 1536);
    float m0c = 1.0f, m1c = 1.0f;
    if (n0 == 1600) {
        m0c = rho[wn * 32 + l16];
        m1c = rho[wn * 32 + l16 + 16];
    }
    const int colb = n0 + wn * 32 + l16;
    const int rowb = m0 + wm * 32 + quad * 4;
    #pragma unroll
    for (int r2 = 0; r2 < 4; r2++) {
        float v00 = acc00[r2], v01 = acc01[r2], v10 = acc10[r2], v11 = acc11[r2];
        if (sig) {
            v00 = m0c / (1.0f + expf(-v00));
            v01 = m1c / (1.0f + expf(-v01));
            v10 = m0c / (1.0f + expf(-v10));
            v11 = m1c / (1.0f + expf(-v11));
        }
        proj[(size_t)(rowb + r2) * NPROJ + colb] = v00;
        proj[(size_t)(rowb + r2) * NPROJ + colb + 16] = v01;
        proj[(size_t)(rowb + 16 + r2) * NPROJ + colb] = v10;
        proj[(size_t)(rowb + 16 + r2) * NPROJ + colb + 16] = v11;
    }
}

// ---------------- Kernel 3: scan — bf16-packed k|q LDS (1 b128/step), 256 threads -----
// R3-measured-good structure + R5 constant folding.
// grid 512 = b(2) x hr(64) x s(4); block 256: vl = tid>>4 (16 v), kl = tid&15 (4 k each)
// vg = {beta*v, mw*gate}; sc4 = {beta*d, d, kq}
__global__ __launch_bounds__(256, 2) void scan_kernel(const float* __restrict__ proj,
        const float* __restrict__ cosw, const float* __restrict__ sinw,
        const float* __restrict__ modew, float* __restrict__ Acomb)
{
    __shared__ uint2 qks[2][CH][16][2];  // per (t,kl): [0]={k0..3 bf16}, [1]={q0..3}  16 KB
    __shared__ float2 vg[2][CH][16];     // {beta*v, mw*gate} per (t, vl)               8 KB
    __shared__ float sc4[2][CH][4];      // [0]=beta*d [1]=d [2]=kq                     1 KB
    __shared__ float obuf[CH][16];       // per-chunk outputs                           2 KB

    const int bi = blockIdx.x;
    const int s  = bi & 3;
    const int hr = (bi >> 2) & 63;
    const int b  = bi >> 8;
    const int h = hr >> 3, r = hr & 7;
    const int tid = threadIdx.x;
    const int vl = tid >> 4;             // 0..15
    const int kl = tid & 15;             // 0..15, low 4 lane bits

    float2v cw0, cw1, sw0, sw1;
    cw0.x = cosw[hr * 64 + kl * 4 + 0]; cw0.y = cosw[hr * 64 + kl * 4 + 1];
    cw1.x = cosw[hr * 64 + kl * 4 + 2]; cw1.y = cosw[hr * 64 + kl * 4 + 3];
    sw0.x = sinw[hr * 64 + kl * 4 + 0]; sw0.y = sinw[hr * 64 + kl * 4 + 1];
    sw1.x = sinw[hr * 64 + kl * 4 + 2]; sw1.y = sinw[hr * 64 + kl * 4 + 3];
    const float mw = modew[hr];
    float2v sr0 = {0,0}, sr1 = {0,0}, si0 = {0,0}, si1 = {0,0};

    const float* pb = proj + (size_t)b * T_ * NPROJ;
    const int qbase = h * 64;
    const int kbase = 512 + h * 64;
    const int vbase = 1024 + h * 64 + s * 16;
    const int gbase = 1664 + h * 64 + s * 16;
    const int boff  = 1536 + h * 8 + r;
    const int goff  = 1600 + h * 8 + r;

    // stage chunk 0 directly global->LDS (fp32 -> packed bf16 for q,k; fold consts)
    {
        #pragma unroll
        for (int rep = 0; rep < 4; rep++) {
            int idx = rep * 256 + tid;
            int t = idx >> 5, sub = idx & 31;
            const float* row = pb + (size_t)t * NPROJ;
            float4 f = *(const float4*)(row + (sub < 16 ? qbase + sub * 4
                                                        : kbase + (sub - 16) * 4));
            uint2 pk2; pk2.x = pack_bf(f.x, f.y); pk2.y = pack_bf(f.z, f.w);
            qks[0][t][sub & 15][sub < 16 ? 1 : 0] = pk2;
        }
        #pragma unroll
        for (int rep = 0; rep < 2; rep++) {
            int idx = rep * 256 + tid;
            int t = idx >> 4, v2 = idx & 15;
            const float* row = pb + (size_t)t * NPROJ;
            float be = row[boff];
            vg[0][t][v2] = make_float2(be * row[vbase + v2], mw * row[gbase + v2]);
        }
        if (tid < CH) {
            const float* row = pb + (size_t)tid * NPROJ;
            float be = row[boff], dd = row[goff];
            sc4[0][tid][0] = be * dd;
            sc4[0][tid][1] = dd;
        }
    }
    __syncthreads();

    float* dstb = Acomb + ((size_t)b * 128) * 512 + h * 64 + s * 16;

    for (int c = 0; c < T_ / CH; c++) {
        const int cb = c & 1, nb = cb ^ 1;
        const bool have = (c + 1 < T_ / CH);

        // --- global prefetch chunk c+1 into registers ---
        float4 g_qk[4]; float g_v[2], g_g[2], g_be[2]; float g_be2 = 0.0f, g_dd = 0.0f;
        if (have) {
            const int t0 = (c + 1) * CH;
            #pragma unroll
            for (int rep = 0; rep < 4; rep++) {
                int idx = rep * 256 + tid;
                int t = idx >> 5, sub = idx & 31;
                const float* row = pb + (size_t)(t0 + t) * NPROJ;
                g_qk[rep] = *(const float4*)(row + (sub < 16 ? qbase + sub * 4
                                                             : kbase + (sub - 16) * 4));
            }
            #pragma unroll
            for (int rep = 0; rep < 2; rep++) {
                int idx = rep * 256 + tid;
                int t = idx >> 4, v2 = idx & 15;
                const float* row = pb + (size_t)(t0 + t) * NPROJ;
                g_v[rep]  = row[vbase + v2];
                g_g[rep]  = row[gbase + v2];
                g_be[rep] = row[boff];
            }
            if (tid < CH) {
                const float* row = pb + (size_t)(t0 + tid) * NPROJ;
                g_be2 = row[boff];
                g_dd  = row[goff];
            }
        }

        // --- hoisted kq_t for this chunk (reads packed bf16) ---
        {
            int t = tid >> 3, j = tid & 7;
            uint4 wa = *(const uint4*)&qks[cb][t][2 * j][0];
            uint4 wb = *(const uint4*)&qks[cb][t][2 * j + 1][0];
            float p = bf_lo(wa.x) * bf_lo(wa.z) + bf_hi(wa.x) * bf_hi(wa.z)
                    + bf_lo(wa.y) * bf_lo(wa.w) + bf_hi(wa.y) * bf_hi(wa.w)
                    + bf_lo(wb.x) * bf_lo(wb.z) + bf_hi(wb.x) * bf_hi(wb.z)
                    + bf_lo(wb.y) * bf_lo(wb.w) + bf_hi(wb.y) * bf_hi(wb.w);
            p = dpp_add<0xB1>(p);   // xor1
            p = dpp_add<0x4E>(p);   // xor2
            p = dpp_add<0x141>(p);  // half-mirror within 8
            if (j == 0) sc4[cb][t][2] = p;
        }
        // --- flush previous chunk's outputs ---
        if (c > 0) {
            #pragma unroll
            for (int rep = 0; rep < 2; rep++) {
                int idx = rep * 256 + tid;
                int t = idx >> 4, v2 = idx & 15;
                atomicAdd(dstb + (size_t)((c - 1) * CH + t) * 512 + v2, obuf[t][v2]);
            }
        }
        __syncthreads();

        // --- 32 steps, single b128 k|q read per step ---
        const float2* vgb = &vg[cb][0][0];
        const float4* svb = (const float4*)&sc4[cb][0][0];

        uint4 w = *(const uint4*)&qks[cb][0][kl][0];
        float4 sv = svb[0];
        float2 vgv = vgb[vl];
        #pragma unroll
        for (int t = 0; t < CH; t++) {
            uint4 w_n; float4 sv_n; float2 vg_n;
            if (t + 1 < CH) {
                w_n = *(const uint4*)&qks[cb][t + 1][kl][0];
                sv_n = svb[t + 1];
                vg_n = vgb[(t + 1) * 16 + vl];
            }

            // unpack bf16 k|q
            float2v k0; k0.x = bf_lo(w.x); k0.y = bf_hi(w.x);
            float2v k1; k1.x = bf_lo(w.y); k1.y = bf_hi(w.y);
            float2v q0; q0.x = bf_lo(w.z); q0.y = bf_hi(w.z);
            float2v q1; q1.x = bf_lo(w.w); q1.y = bf_hi(w.w);

            float2v t1 = cw0 * sr0 - sw0 * si0;
            float2v u1 = sw0 * sr0 + cw0 * si0;
            float2v t2 = cw1 * sr1 - sw1 * si1;
            float2v u2 = sw1 * sr1 + cw1 * si1;

            float2v pk2 = t1 * k0 + t2 * k1;
            float2v pq2 = t1 * q0 + t2 * q1;
            float pk = pk2.x + pk2.y;
            float pq = pq2.x + pq2.y;
            pk = dpp_add<0xB1>(pk);  pq = dpp_add<0xB1>(pq);   // xor1
            pk = dpp_add<0x4E>(pk);  pq = dpp_add<0x4E>(pq);   // xor2
            pk = dpp_add<0x141>(pk); pq = dpp_add<0x141>(pq);  // xor4
            pk = dpp_add<0x140>(pk); pq = dpp_add<0x140>(pq);  // xor8 (mirror in 16)

            const float d = sv.y;
            float2v d2; d2.x = d; d2.y = d;
            float2v rr0 = d2 * t1, rr1 = d2 * t2;
            si0 = d2 * u1; si1 = d2 * u2;
            const float sc = vgv.x - sv.x * pk;       // beta*v - (beta*d)*pk
            float2v sc2; sc2.x = sc; sc2.y = sc;
            sr0 = rr0 + sc2 * k0;
            sr1 = rr1 + sc2 * k1;
            const float rp = d * pq + sc * sv.z;      // = sum(sr_new * q)
            if (kl == 0) obuf[t][vl] = rp * vgv.y;    // * mw*gate (pre-folded)

            w = w_n; sv = sv_n; vgv = vg_n;
        }

        // --- write staged registers into the other LDS buffer (convert to bf16) ---
        if (have) {
            #pragma unroll
            for (int rep = 0; rep < 4; rep++) {
                int idx = rep * 256 + tid;
                int t = idx >> 5, sub = idx & 31;
                float4 f = g_qk[rep];
                uint2 pk2; pk2.x = pack_bf(f.x, f.y); pk2.y = pack_bf(f.z, f.w);
                qks[nb][t][sub & 15][sub < 16 ? 1 : 0] = pk2;
            }
            #pragma unroll
            for (int rep = 0; rep < 2; rep++) {
                int idx = rep * 256 + tid;
                int t = idx >> 4, v2 = idx & 15;
                vg[nb][t][v2] = make_float2(g_be[rep] * g_v[rep], mw * g_g[rep]);
            }
            if (tid < CH) {
                sc4[nb][tid][0] = g_be2 * g_dd;
                sc4[nb][tid][1] = g_dd;
            }
        }
        __syncthreads();
    }
    // final flush
    #pragma unroll
    for (int rep = 0; rep < 2; rep++) {
        int idx = rep * 256 + tid;
        int t = idx >> 4, v2 = idx & 15;
        atomicAdd(dstb + (size_t)(3 * CH + t) * 512 + v2, obuf[t][v2]);
    }
}

// ---------------- Kernel 4: output GEMM, depth-2 prefetch (NAMED regs) ----------------
__global__ __launch_bounds__(256, 2) void out_mfma(const float* __restrict__ Af,
        const ushort* __restrict__ BTb, float* __restrict__ C)
{
    __shared__ ushort sA[2][64][40];
    __shared__ ushort sB[2][64][40];
    const int n0 = blockIdx.x * 64, m0 = blockIdx.y * 64;
    const int tid = threadIdx.x;
    const int lane = tid & 63, w = tid >> 6;
    const int wm = w & 1, wn = w >> 1;
    const int l16 = lane & 15, quad = lane >> 4;
    const int srow = tid >> 2, skq = (tid & 3) * 8;
    const float* Ag = Af + (size_t)(m0 + srow) * 512 + skq;
    const ushort* Bg = BTb + (size_t)(n0 + srow) * 512 + skq;
    float4 fa0A = *(const float4*)Ag;
    float4 fa1A = *(const float4*)(Ag + 4);
    short8 rbA  = *(const short8*)Bg;
    float4 fa0B = *(const float4*)(Ag + 32);
    float4 fa1B = *(const float4*)(Ag + 36);
    short8 rbB  = *(const short8*)(Bg + 32);
    float4v acc00 = {0,0,0,0}, acc01 = {0,0,0,0}, acc10 = {0,0,0,0}, acc11 = {0,0,0,0};
    for (int kt = 0; kt < 16; kt += 2) {
        {
            short8 ra;
            ra[0]=f2bf(fa0A.x); ra[1]=f2bf(fa0A.y); ra[2]=f2bf(fa0A.z); ra[3]=f2bf(fa0A.w);
            ra[4]=f2bf(fa1A.x); ra[5]=f2bf(fa1A.y); ra[6]=f2bf(fa1A.z); ra[7]=f2bf(fa1A.w);
            *(short8*)&sA[0][srow][skq] = ra;
            *(short8*)&sB[0][srow][skq] = rbA;
        }
        __syncthreads();
        if (kt + 2 < 16) {
            fa0A = *(const float4*)(Ag + (kt + 2) * 32);
            fa1A = *(const float4*)(Ag + (kt + 2) * 32 + 4);
            rbA  = *(const short8*)(Bg + (kt + 2) * 32);
        }
        {
            short8 a0 = *(const short8*)&sA[0][wm * 32 + l16][quad * 8];
            short8 a1 = *(const short8*)&sA[0][wm * 32 + 16 + l16][quad * 8];
            short8 b0 = *(const short8*)&sB[0][wn * 32 + l16][quad * 8];
            short8 b1 = *(const short8*)&sB[0][wn * 32 + 16 + l16][quad * 8];
            acc00 = __builtin_amdgcn_mfma_f32_16x16x32_bf16(a0, b0, acc00, 0, 0, 0);
            acc01 = __builtin_amdgcn_mfma_f32_16x16x32_bf16(a0, b1, acc01, 0, 0, 0);
            acc10 = __builtin_amdgcn_mfma_f32_16x16x32_bf16(a1, b0, acc10, 0, 0, 0);
            acc11 = __builtin_amdgcn_mfma_f32_16x16x32_bf16(a1, b1, acc11, 0, 0, 0);
        }
        {
            short8 ra;
            ra[0]=f2bf(fa0B.x); ra[1]=f2bf(fa0B.y); ra[2]=f2bf(fa0B.z); ra[3]=f2bf(fa0B.w);
            ra[4]=f2bf(fa1B.x); ra[5]=f2bf(fa1B.y); ra[6]=f2bf(fa1B.z); ra[7]=f2bf(fa1B.w);
            *(short8*)&sA[1][srow][skq] = ra;
            *(short8*)&sB[1][srow][skq] = rbB;
        }
        __syncthreads();
        if (kt + 3 < 16) {
            fa0B = *(const float4*)(Ag + (kt + 3) * 32);
            fa1B = *(const float4*)(Ag + (kt + 3) * 32 + 4);
            rbB  = *(const short8*)(Bg + (kt + 3) * 32);
        }
        {
            short8 a0 = *(const short8*)&sA[1][wm * 32 + l16][quad * 8];
            short8 a1 = *(const short8*)&sA[1][wm * 32 + 16 + l16][quad * 8];
            short8 b0 = *(const short8*)&sB[1][wn * 32 + l16][quad * 8];
            short8 b1 = *(const short8*)&sB[1][wn * 32 + 16 + l16][quad * 8];
            acc00 = __builtin_amdgcn_mfma_f32_16x16x32_bf16(a0, b0, acc00, 0, 0, 0);
            acc01 = __builtin_amdgcn_mfma_f32_16x16x32_bf16(a0, b1, acc01, 0, 0, 0);
            acc10 = __builtin_amdgcn_mfma_f32_16x16x32_bf16(a1, b0, acc10, 0, 0, 0);
            acc11 = __builtin_amdgcn_mfma_f32_16x16x32_bf16(a1, b1, acc11, 0, 0, 0);
        }
    }
    const int colb = n0 + wn * 32 + l16;
    const int rowb = m0 + wm * 32 + quad * 4;
    #pragma unroll
    for (int r2 = 0; r2 < 4; r2++) {
        C[(size_t)(rowb + r2) * 1024 + colb] = acc00[r2];
        C[(size_t)(rowb + r2) * 1024 + colb + 16] = acc01[r2];
        C[(size_t)(rowb + 16 + r2) * 1024 + colb] = acc10[r2];
        C[(size_t)(rowb + 16 + r2) * 1024 + colb + 16] = acc11[r2];
    }
}

extern "C" void kernel_launch(void* const* d_in, const int* in_sizes, int n_in,
                              void* d_out, int out_size, void* d_ws, size_t ws_size,
                              hipStream_t stream) {
    const float* x   = (const float*)d_in[0];
    const float* Wq  = (const float*)d_in[1];
    const float* Wk  = (const float*)d_in[2];
    const float* Wv  = (const float*)d_in[3];
    const float* Wb  = (const float*)d_in[4];
    const float* Wtg = (const float*)d_in[5];
    const float* ml  = (const float*)d_in[6];
    const float* ldc = (const float*)d_in[7];
    const float* ols = (const float*)d_in[8];
    const float* Wg  = (const float*)d_in[9];
    const float* Wo  = (const float*)d_in[10];
    float* out = (float*)d_out;

    float* ws = (float*)d_ws;
    float* proj    = ws;                                 // 557056 f
    float* cosw    = proj + 256 * NPROJ;                 // 4096
    float* sinw    = cosw + 4096;                        // 4096
    float* rho     = sinw + 4096;                        // 64
    float* modew   = rho + 64;                           // 64
    ushort* xb     = (ushort*)(modew + 64);              // 262144 us = 131072 f
    ushort* wotb   = (ushort*)((float*)xb + 131072);     // 524288 us = 262144 f
    float*  Acomb  = (float*)wotb + 262144;              // 131072 f
    ushort* wtb    = (ushort*)(Acomb + 131072);          // 2228224 us = 1114112 f

    prep_kernel<<<784, 256, 0, stream>>>(x, Wq, Wk, Wv, Wb, Wtg, Wg, Wo,
                                         ml, ldc, ols, cosw, sinw, rho, modew,
                                         xb, wtb, wotb, Acomb);
    proj_mfma<<<dim3(34, 4), 256, 0, stream>>>(xb, wtb, rho, proj);
    scan_kernel<<<512, 256, 0, stream>>>(proj, cosw, sinw, modew, Acomb);
    out_mfma<<<dim3(16, 4), 256, 0, stream>>>(Acomb, wotb, out);
}